// Round 4
// baseline (438.354 us; speedup 1.0000x reference)
//
#include <hip/hip_runtime.h>
#include <stdint.h>
#include <stddef.h>

// CapsuleFC: B=64, N_IN=2048, D_IN=16, N_OUT=64, D_OUT=16
constexpr int B_ = 64, N_ = 2048, A_ = 16, M_ = 64, D_ = 16;
constexpr float SCALE_ = 0.25f;   // 1/sqrt(16)
constexpr float EPS_ = 1e-6f;

typedef float f32x4 __attribute__((ext_vector_type(4)));

#define GL16(g, l)                                                             \
  __builtin_amdgcn_global_load_lds((__attribute__((address_space(1))) void*)(g), \
                                   (__attribute__((address_space(3))) void*)(l), \
                                   16, 0, 0)
#define GL4(g, l)                                                              \
  __builtin_amdgcn_global_load_lds((__attribute__((address_space(1))) void*)(g), \
                                   (__attribute__((address_space(3))) void*)(l), \
                                   4, 0, 0)

// counted vmcnt wait (literal N) — never drain to 0 in the main loop (T4)
#define WV(n) asm volatile("s_waitcnt vmcnt(" #n ")" ::: "memory")
// compiler fence + hw barrier: pins all memory ops (incl. gload_lds/stores)
#define BAR() do {                        \
    asm volatile("" ::: "memory");        \
    __builtin_amdgcn_s_barrier();         \
    asm volatile("" ::: "memory");        \
    __builtin_amdgcn_sched_barrier(0);    \
  } while (0)

// Stage quarter qq (4 a-planes, 16KB) of w[n] into ring slot wbuf[qq].
// LDS dest linear; global SOURCE pre-swizzled (involution on bits[6:4] keyed
// by bits[9:7]) so ds_read_b128 at stride-64 rows is bank-balanced (G4/T2).
#define ISSUE_W(n_, qq_)                                                       \
  { const char* ws_ = (const char*)w + ((size_t)(n_) << 16) + ((size_t)(qq_) << 14); \
    char* lb_ = wbuf[(qq_)] + wv * 1024;                                       \
    _Pragma("unroll")                                                          \
    for (int i_ = 0; i_ < 4; ++i_) {                                           \
      const uint32_t P_ = (uint32_t)(i_ * 4096 + tid * 16);                    \
      const uint32_t S_ = P_ ^ (((P_ >> 7) & 7u) << 4);                        \
      GL16(ws_ + S_, lb_ + i_ * 4096);                                         \
    } }

// Stage input[b0g..b0g+15][n][0..15] (1KB) into in_lds[n&1]. 1 load/thread.
#define ISSUE_IN(n_)                                                           \
  { const float* src_ = input + ((size_t)(b0g + (tid >> 4)) * N_ + (n_)) * A_ + (tid & 15); \
    GL4(src_, in_lds[(n_) & 1] + wv * 256); }

// Compute quarter qq of n = n0+k: votes partial; at qq==3 score+softmax+acc.
#define COMPQ(k_, qq_, DOSCORE_)                                               \
  { const int kk_ = (k_);                                                      \
    const char* lb_ = wbuf[(qq_)];                                             \
    f32x4 ibv_[4];                                                             \
    _Pragma("unroll")                                                          \
    for (int bi = 0; bi < 4; ++bi)                                             \
      ibv_[bi] = *(const f32x4*)(in_lds[kk_ & 1] + (wv * 4 + bi) * 64 + (qq_) * 16); \
    if ((qq_) == 0) {                                                          \
      _Pragma("unroll") for (int bi = 0; bi < 4; ++bi)                         \
      _Pragma("unroll") for (int d = 0; d < 16; ++d) v[bi][d] = 0.f;           \
    }                                                                          \
    _Pragma("unroll")                                                          \
    for (int al = 0; al < 4; ++al) {                                           \
      f32x4 wr_[4];                                                            \
      _Pragma("unroll")                                                        \
      for (int j = 0; j < 4; ++j)                                              \
        wr_[j] = *(const f32x4*)(lb_ + al * 4096 + offj[j]);                   \
      _Pragma("unroll")                                                        \
      for (int bi = 0; bi < 4; ++bi) {                                         \
        const float x_ = ibv_[bi][al];                                         \
        _Pragma("unroll")                                                      \
        for (int j = 0; j < 4; ++j) {                                          \
          v[bi][4*j+0] += x_ * wr_[j].x; v[bi][4*j+1] += x_ * wr_[j].y;        \
          v[bi][4*j+2] += x_ * wr_[j].z; v[bi][4*j+3] += x_ * wr_[j].w;        \
        }                                                                      \
      }                                                                        \
    }                                                                          \
    if (DOSCORE_) {                                                            \
      const int n_ = n0 + kk_;                                                 \
      _Pragma("unroll")                                                        \
      for (int bi = 0; bi < 4; ++bi) {                                         \
        float s_ = 0.f;                                                        \
        _Pragma("unroll") for (int d = 0; d < 16; ++d) s_ += v[bi][d] * cv[bi][d]; \
        s_ *= SCALE_;                                                          \
        /* |s| <~ 1 (s ~ N(0,0.18)) -> exp w/o max-sub is safe; e^mx cancels */\
        const float e_ = __expf(s_);                                           \
        const float ena_ = e_ * na[bi];                                        \
        float Ps_ = ena_;                                                      \
        _Pragma("unroll")                                                      \
        for (int off = 32; off >= 1; off >>= 1) Ps_ += __shfl_xor(Ps_, off, 64); \
        const float qkv_ = ena_ / Ps_;  /* 1e-10*Es term ~2e-10 rel: dropped */\
        qk_out[((size_t)(b0 + bi) * N_ + n_) * M_ + lane] = qkv_;              \
        float ab_ = *(const float*)(ca_lds + ((((wv * 4 + bi) << CL2) | kk_) << 2)); \
        ab_ = fminf(fmaxf(ab_, EPS_), 1.0f - EPS_);                            \
        const float wq_ = qkv_ * ab_;                                          \
        _Pragma("unroll") for (int d = 0; d < 16; ++d) acc[bi][d] += wq_ * v[bi][d]; \
      }                                                                        \
    } }

// grid: 4*nch blocks (4 bgroups x nch chunks, co-XCD per chunk).
// block: 256 threads = 4 waves; wave wv owns b-quad; lane l owns m=l.
// Ring of 4 x 16KB quarter-slabs, depth-3 counted-vmcnt prefetch.
__global__ __launch_bounds__(256, 2) void caps_main(
    const float* __restrict__ input,   // [B,N,A]
    const float* __restrict__ cact,    // [B,N]
    const float* __restrict__ ncv,     // [B,M,D]
    const float* __restrict__ nact,    // [B,M]
    const float* __restrict__ w,       // [N,A,M,D]
    float* __restrict__ qk_out,        // [B,N,M]
    float* __restrict__ partial,       // [nch,B,M,D]
    int C, int CL2, int nch)
{
  __shared__ __align__(16) char wbuf[4][16384];  // ring: quarter-slabs
  __shared__ __align__(16) char in_lds[2][1024]; // input[16b][16a] x2 slots
  __shared__ __align__(16) char ca_lds[4096];    // cact[16b][C<=64]

  const int tid  = threadIdx.x;
  const int lane = tid & 63;
  const int wv   = __builtin_amdgcn_readfirstlane(tid >> 6);

  // XCD co-location: 4 bg blocks of chunk ch share flat%8 -> same XCD
  const int flat = blockIdx.x;
  int bg, ch;
  if (nch & 7) { bg = flat & 3; ch = flat >> 2; }
  else { const int x = flat & 7, r = flat >> 3; bg = r & 3; ch = (r >> 2) * 8 + x; }

  const int b0g = bg * 16;
  const int b0  = b0g + wv * 4;
  const int n0  = ch * C;

  // swizzled LDS read offsets (matches stage-side involution)
  int offj[4];
#pragma unroll
  for (int j = 0; j < 4; ++j)
    offj[j] = (lane * 64 + j * 16) ^ (((lane >> 1) & 7) << 4);

  // loop-invariant per-(b,m) data in registers (pre-loop loads are OLDER
  // than all staged loads -> first counted wait force-completes them)
  float na[4], cv[4][16];
#pragma unroll
  for (int bi = 0; bi < 4; ++bi) {
    na[bi] = nact[(b0 + bi) * M_ + lane];
    const f32x4* np4 = (const f32x4*)(ncv + ((size_t)(b0 + bi) * M_ + lane) * D_);
#pragma unroll
    for (int j = 0; j < 4; ++j) {
      const f32x4 t = np4[j];
      cv[bi][4*j+0] = t.x; cv[bi][4*j+1] = t.y; cv[bi][4*j+2] = t.z; cv[bi][4*j+3] = t.w;
    }
  }

  float acc[4][16], v[4][16];
#pragma unroll
  for (int bi = 0; bi < 4; ++bi)
#pragma unroll
    for (int d = 0; d < 16; ++d) acc[bi][d] = 0.f;

  // ---- prologue staging: cact slab, then S(0)+in(0), S(1), S(2)
  for (int r = 0; r * 256 < 16 * C; ++r) {
    const int idx = r * 256 + tid;
    const float* src = cact + (size_t)(b0g + (idx >> CL2)) * N_ + n0 + (idx & (C - 1));
    GL4(src, ca_lds + r * 1024 + wv * 256);
  }
  ISSUE_W(n0, 0); ISSUE_IN(n0);
  ISSUE_W(n0, 1);
  ISSUE_W(n0, 2);

  // ---- k = 0 (peeled: shallow-history X)
  ISSUE_W(n0, 3);                          WV(12); BAR(); COMPQ(0, 0, false); BAR();
  ISSUE_W(n0 + 1, 0); ISSUE_IN(n0 + 1);    WV(13); BAR(); COMPQ(0, 1, false); BAR();
  ISSUE_W(n0 + 1, 1);                      WV(13); BAR(); COMPQ(0, 2, false); BAR();
  ISSUE_W(n0 + 1, 2);                      WV(13); BAR(); COMPQ(0, 3, true);  BAR();

  // ---- steady state k = 1 .. C-2: X = {16,17,17,13}
  for (int k = 1; k < C - 1; ++k) {
    const int n = n0 + k;
    ISSUE_W(n, 3);                         WV(16); BAR(); COMPQ(k, 0, false); BAR();
    ISSUE_W(n + 1, 0); ISSUE_IN(n + 1);    WV(17); BAR(); COMPQ(k, 1, false); BAR();
    ISSUE_W(n + 1, 1);                     WV(17); BAR(); COMPQ(k, 2, false); BAR();
    ISSUE_W(n + 1, 2);                     WV(13); BAR(); COMPQ(k, 3, true);  BAR();
  }

  // ---- tail k = C-1: X = {16,12,8,0}
  {
    const int k = C - 1;
    ISSUE_W(n0 + k, 3);                    WV(16); BAR(); COMPQ(k, 0, false); BAR();
    /* no issue */                         WV(12); BAR(); COMPQ(k, 1, false); BAR();
    /* no issue */                         WV(8);  BAR(); COMPQ(k, 2, false); BAR();
    /* no issue */                         WV(0);  BAR(); COMPQ(k, 3, true);  BAR();
  }

  // partial[ch][b][m][d]
#pragma unroll
  for (int bi = 0; bi < 4; ++bi) {
    float* pp = partial + (((size_t)ch * B_ + (b0 + bi)) * M_ + lane) * D_;
#pragma unroll
    for (int j = 0; j < 4; ++j) {
      f32x4 t;
      t.x = acc[bi][4*j+0]; t.y = acc[bi][4*j+1];
      t.z = acc[bi][4*j+2]; t.w = acc[bi][4*j+3];
      __builtin_nontemporal_store(t, (f32x4*)pp + j);
    }
  }
}

__global__ void caps_reduce(const float* __restrict__ part,
                            const float* __restrict__ nain,
                            float* __restrict__ out, int nch)
{
  const int i = blockIdx.x * 256 + threadIdx.x;  // one thread per out[b,m,d]
  float s = 0.f;
  for (int c = 0; c < nch; ++c) s += part[(size_t)c * (B_ * M_ * D_) + i];
  out[i] = s;
  if (i < B_ * M_) out[B_ * M_ * D_ + i] = nain[i];  // next_act passthrough
}

extern "C" void kernel_launch(void* const* d_in, const int* in_sizes, int n_in,
                              void* d_out, int out_size, void* d_ws, size_t ws_size,
                              hipStream_t stream)
{
  const float* input = (const float*)d_in[0];
  const float* cact  = (const float*)d_in[1];
  const float* ncv   = (const float*)d_in[2];
  const float* nact  = (const float*)d_in[3];
  const float* w     = (const float*)d_in[4];

  float* out     = (float*)d_out;
  float* qk_out  = out + (B_ * M_ * D_) + (B_ * M_);   // after out and next_act
  float* partial = (float*)d_ws;

  int nch = 128;  // power of two; C = N/nch >= 16 keeps peel structure valid
  while ((size_t)nch * (size_t)(B_ * M_ * D_) * sizeof(float) > ws_size && nch > 32) nch >>= 1;
  const int C = N_ / nch;
  int cl2 = 0; while ((1 << cl2) < C) ++cl2;

  hipLaunchKernelGGL(caps_main, dim3(4 * nch), dim3(256), 0, stream,
                     input, cact, ncv, nact, w, qk_out, partial, C, cl2, nch);
  hipLaunchKernelGGL(caps_reduce, dim3(B_ * M_ * D_ / 256), dim3(256), 0, stream,
                     partial, nact, out, nch);
}